// Round 2
// baseline (4696.617 us; speedup 1.0000x reference)
//
#include <hip/hip_runtime.h>
#include <hip/hip_bf16.h>

#define N_NODES 100000
#define N_EDGES 1600000
#define HID 64
#define OUT_CH 32

// ---- edge_index dtype probe: int64 => all odd 32-bit words are 0 -----------
__global__ void detect_kernel(const int* __restrict__ ei, int* __restrict__ flag) {
    int i = threadIdx.x;  // 0..63
    int v = ei[2 * i + 1];
    unsigned long long ball = __ballot(v == 0);
    if (i == 0) *flag = (ball == ~0ull) ? 1 : 0;  // 1 = int64, 0 = int32
}

__device__ __forceinline__ int get_idx(const int* __restrict__ ei, int is64, long long pos) {
    // pos is the logical element index into the flat [2, N_EDGES] array
    return is64 ? ei[2 * pos] : ei[pos];
}

// ---- degree --------------------------------------------------------------
__global__ void deg_kernel(const int* __restrict__ ei, const int* __restrict__ flag,
                           float* __restrict__ deg) {
    int e = blockIdx.x * blockDim.x + threadIdx.x;
    if (e >= N_EDGES) return;
    int is64 = *flag;
    int d = get_idx(ei, is64, (long long)N_EDGES + e);
    atomicAdd(&deg[d], 1.0f);
}

// ---- scatter-add: 16 threads per edge, float4 per thread ------------------
__global__ void scatter_kernel(const float* __restrict__ h, const int* __restrict__ ei,
                               const int* __restrict__ flag, float* __restrict__ agg) {
    long long t = (long long)blockIdx.x * blockDim.x + threadIdx.x;
    int e = (int)(t >> 4);
    if (e >= N_EDGES) return;
    int c = ((int)t & 15) << 2;
    int is64 = *flag;
    int s = get_idx(ei, is64, e);
    int d = get_idx(ei, is64, (long long)N_EDGES + e);
    float4 v = *(const float4*)(h + (long long)s * HID + c);
    float* ap = agg + (long long)d * HID + c;
    atomicAdd(ap + 0, v.x);
    atomicAdd(ap + 1, v.y);
    atomicAdd(ap + 2, v.z);
    atomicAdd(ap + 3, v.w);
}

// ---- SAGE layer: out = relu(inv_deg*(agg@Wl) + h@Wr + b) ------------------
// 256 threads = 4 nodes x 64 output channels. out may alias h (in-place):
// each node's row is owned by exactly one wave64; lock-step execution means
// all k-loop loads complete before any lane's store.
__global__ void __launch_bounds__(256) sage_layer_kernel(
        const float* __restrict__ agg, const float* __restrict__ deg,
        const float* __restrict__ h,
        const float* __restrict__ Wl, const float* __restrict__ Wr,
        const float* __restrict__ b, float* __restrict__ out) {
    __shared__ float sWl[HID * HID];
    __shared__ float sWr[HID * HID];
    __shared__ float sb[HID];
    int tid = threadIdx.x;
    for (int i = tid; i < HID * HID; i += 256) {
        sWl[i] = Wl[i];
        sWr[i] = Wr[i];
    }
    if (tid < HID) sb[tid] = b[tid];
    __syncthreads();

    int node = blockIdx.x * 4 + (tid >> 6);
    if (node >= N_NODES) return;
    int o = tid & 63;
    float inv = 1.0f / fmaxf(deg[node], 1.0f);
    const float* ar = agg + (long long)node * HID;
    const float* hr = h + (long long)node * HID;
    float accl = 0.f, accr = 0.f;
#pragma unroll 8
    for (int k = 0; k < HID; k++) {
        accl += ar[k] * sWl[k * HID + o];
        accr += hr[k] * sWr[k * HID + o];
    }
    float v = accl * inv + accr + sb[o];
    out[(long long)node * HID + o] = fmaxf(v, 0.0f);
}

// ---- final head: out = h @ Wlin + blin (fp32 out) -------------------------
__global__ void __launch_bounds__(256) final_kernel(
        const float* __restrict__ h, const float* __restrict__ W,
        const float* __restrict__ b, float* __restrict__ out) {
    __shared__ float sW[HID * OUT_CH];
    __shared__ float sb[OUT_CH];
    int tid = threadIdx.x;
    for (int i = tid; i < HID * OUT_CH; i += 256) sW[i] = W[i];
    if (tid < OUT_CH) sb[tid] = b[tid];
    __syncthreads();

    int node = blockIdx.x * 8 + (tid >> 5);
    if (node >= N_NODES) return;
    int o = tid & 31;
    const float* hr = h + (long long)node * HID;
    float acc = sb[o];
#pragma unroll 8
    for (int k = 0; k < HID; k++) acc += hr[k] * sW[k * OUT_CH + o];
    out[(long long)node * OUT_CH + o] = acc;
}

extern "C" void kernel_launch(void* const* d_in, const int* in_sizes, int n_in,
                              void* d_out, int out_size, void* d_ws, size_t ws_size,
                              hipStream_t stream) {
    const float* x    = (const float*)d_in[0];
    const int*   ei   = (const int*)d_in[1];
    const float* Wl1  = (const float*)d_in[2];
    const float* Wr1  = (const float*)d_in[3];
    const float* b1   = (const float*)d_in[4];
    const float* Wl2  = (const float*)d_in[5];
    const float* Wr2  = (const float*)d_in[6];
    const float* b2   = (const float*)d_in[7];
    const float* Wl3  = (const float*)d_in[8];
    const float* Wr3  = (const float*)d_in[9];
    const float* b3   = (const float*)d_in[10];
    const float* Wlin = (const float*)d_in[11];
    const float* blin = (const float*)d_in[12];
    float* out = (float*)d_out;

    // workspace layout (floats), all offsets multiples of 128 elements
    float* wsf  = (float*)d_ws;
    int*   flag = (int*)d_ws;                       // [0]
    float* deg  = wsf + 128;                        // 100096 floats
    float* agg  = deg + 100096;                     // N_NODES*HID
    float* feat = agg + (size_t)N_NODES * HID;      // N_NODES*HID
    // total: 128 + 100096 + 2*6400000 floats = ~51.6 MB

    const int SCAT_BLOCKS  = (N_EDGES * 16) / 256;   // 100000
    const int LAYER_BLOCKS = (N_NODES + 3) / 4;      // 25000
    const int FINAL_BLOCKS = (N_NODES + 7) / 8;      // 12500
    const size_t AGG_BYTES = (size_t)N_NODES * HID * 4;

    detect_kernel<<<1, 64, 0, stream>>>(ei, flag);

    hipMemsetAsync(deg, 0, (size_t)N_NODES * 4, stream);
    deg_kernel<<<(N_EDGES + 255) / 256, 256, 0, stream>>>(ei, flag, deg);

    // layer 1: x -> feat
    hipMemsetAsync(agg, 0, AGG_BYTES, stream);
    scatter_kernel<<<SCAT_BLOCKS, 256, 0, stream>>>(x, ei, flag, agg);
    sage_layer_kernel<<<LAYER_BLOCKS, 256, 0, stream>>>(agg, deg, x, Wl1, Wr1, b1, feat);

    // layer 2: feat -> feat (in-place)
    hipMemsetAsync(agg, 0, AGG_BYTES, stream);
    scatter_kernel<<<SCAT_BLOCKS, 256, 0, stream>>>(feat, ei, flag, agg);
    sage_layer_kernel<<<LAYER_BLOCKS, 256, 0, stream>>>(agg, deg, feat, Wl2, Wr2, b2, feat);

    // layer 3: feat -> feat (in-place)
    hipMemsetAsync(agg, 0, AGG_BYTES, stream);
    scatter_kernel<<<SCAT_BLOCKS, 256, 0, stream>>>(feat, ei, flag, agg);
    sage_layer_kernel<<<LAYER_BLOCKS, 256, 0, stream>>>(agg, deg, feat, Wl3, Wr3, b3, feat);

    // head
    final_kernel<<<FINAL_BLOCKS, 256, 0, stream>>>(feat, Wlin, blin, out);
}

// Round 3
// 634.708 us; speedup vs baseline: 7.3996x; 7.3996x over previous
//
#include <hip/hip_runtime.h>
#include <hip/hip_bf16.h>

#define N_NODES 100000
#define N_EDGES 1600000
#define HID 64
#define OUT_CH 32
#define NBLK_SCAN ((N_NODES + 255) / 256)   // 391

// ---- edge_index dtype probe: int64 => all odd 32-bit words are 0 -----------
__global__ void detect_kernel(const int* __restrict__ ei, int* __restrict__ flag) {
    int i = threadIdx.x;  // 0..63
    int v = ei[2 * i + 1];
    unsigned long long ball = __ballot(v == 0);
    if (i == 0) *flag = (ball == ~0ull) ? 1 : 0;  // 1 = int64, 0 = int32
}

__device__ __forceinline__ int get_idx(const int* __restrict__ ei, int is64, long long pos) {
    return is64 ? ei[2 * pos] : ei[pos];
}

// ---- CSR build ------------------------------------------------------------
__global__ void count_kernel(const int* __restrict__ ei, const int* __restrict__ flag,
                             int* __restrict__ counts) {
    int e = blockIdx.x * blockDim.x + threadIdx.x;
    if (e >= N_EDGES) return;
    int is64 = *flag;
    int d = get_idx(ei, is64, (long long)N_EDGES + e);
    atomicAdd(&counts[d], 1);
}

__global__ void blockscan_kernel(const int* __restrict__ counts, int* __restrict__ off,
                                 int* __restrict__ bsum) {
    __shared__ int s[256];
    int tid = threadIdx.x;
    int i = blockIdx.x * 256 + tid;
    int v = (i < N_NODES) ? counts[i] : 0;
    s[tid] = v;
    __syncthreads();
    for (int d = 1; d < 256; d <<= 1) {
        int t = (tid >= d) ? s[tid - d] : 0;
        __syncthreads();
        s[tid] += t;
        __syncthreads();
    }
    if (i < N_NODES) off[i] = s[tid] - v;  // exclusive within block
    if (tid == 255) bsum[blockIdx.x] = s[255];
}

__global__ void topscan_kernel(int* __restrict__ bsum) {
    __shared__ int s[512];
    int tid = threadIdx.x;
    int v = (tid < NBLK_SCAN) ? bsum[tid] : 0;
    s[tid] = v;
    __syncthreads();
    for (int d = 1; d < 512; d <<= 1) {
        int t = (tid >= d) ? s[tid - d] : 0;
        __syncthreads();
        s[tid] += t;
        __syncthreads();
    }
    if (tid < NBLK_SCAN) bsum[tid] = s[tid] - v;  // exclusive block offsets
}

__global__ void addback_kernel(int* __restrict__ off, const int* __restrict__ bsum,
                               int* __restrict__ cursor) {
    int i = blockIdx.x * 256 + threadIdx.x;
    if (i < N_NODES) {
        int o = off[i] + bsum[i >> 8];
        off[i] = o;
        cursor[i] = o;
    }
    if (i == 0) off[N_NODES] = N_EDGES;
}

__global__ void fill_kernel(const int* __restrict__ ei, const int* __restrict__ flag,
                            int* __restrict__ cursor, int* __restrict__ csr) {
    int e = blockIdx.x * blockDim.x + threadIdx.x;
    if (e >= N_EDGES) return;
    int is64 = *flag;
    int s = get_idx(ei, is64, e);
    int d = get_idx(ei, is64, (long long)N_EDGES + e);
    int pos = atomicAdd(&cursor[d], 1);
    csr[pos] = s;
}

// ---- gather-aggregate: one wave per node, lane = channel; inv_deg folded --
__global__ void __launch_bounds__(256) gather_kernel(
        const float* __restrict__ h, const int* __restrict__ off,
        const int* __restrict__ csr, float* __restrict__ agg) {
    int node = blockIdx.x * 4 + (threadIdx.x >> 6);
    if (node >= N_NODES) return;
    int o = threadIdx.x & 63;
    int off0 = off[node], off1 = off[node + 1];
    float acc = 0.f;
    int e = off0;
    int end4 = off0 + ((off1 - off0) & ~3);
    for (; e < end4; e += 4) {
        int s0 = csr[e], s1 = csr[e + 1], s2 = csr[e + 2], s3 = csr[e + 3];
        float v0 = h[(size_t)s0 * HID + o];
        float v1 = h[(size_t)s1 * HID + o];
        float v2 = h[(size_t)s2 * HID + o];
        float v3 = h[(size_t)s3 * HID + o];
        acc += v0 + v1 + v2 + v3;
    }
    for (; e < off1; ++e) acc += h[(size_t)csr[e] * HID + o];
    float inv = 1.f / fmaxf((float)(off1 - off0), 1.f);
    agg[(size_t)node * HID + o] = acc * inv;
}

// ---- layer GEMM: out = relu(agg@Wl + h@Wr + b), 64-node LDS tile ----------
// Transposed tiles with stride 68 (16B-aligned float4, <=2-way bank alias).
#define LT 68
__global__ void __launch_bounds__(256) layer_kernel(
        const float* __restrict__ agg, const float* __restrict__ h,
        const float* __restrict__ Wl, const float* __restrict__ Wr,
        const float* __restrict__ bias, float* __restrict__ out) {
    __shared__ float sWl[HID * HID];
    __shared__ float sWr[HID * HID];
    __shared__ float sAT[HID * LT];
    __shared__ float sHT[HID * LT];
    __shared__ float sb[HID];
    int tid = threadIdx.x;
    for (int i = tid; i < HID * HID; i += 256) {
        sWl[i] = Wl[i];
        sWr[i] = Wr[i];
    }
    if (tid < HID) sb[tid] = bias[tid];

    int node0 = blockIdx.x * 64;
    int rr = tid >> 4;           // 0..15
    int cc = (tid & 15) << 2;    // 0,4,...,60
#pragma unroll
    for (int p = 0; p < 4; ++p) {
        int r = rr + p * 16;
        int n = node0 + r;
        float4 a, hh;
        if (n < N_NODES) {
            a = *(const float4*)(agg + (size_t)n * HID + cc);
            hh = *(const float4*)(h + (size_t)n * HID + cc);
        } else {
            a = make_float4(0, 0, 0, 0);
            hh = make_float4(0, 0, 0, 0);
        }
        sAT[(cc + 0) * LT + r] = a.x;  sAT[(cc + 1) * LT + r] = a.y;
        sAT[(cc + 2) * LT + r] = a.z;  sAT[(cc + 3) * LT + r] = a.w;
        sHT[(cc + 0) * LT + r] = hh.x; sHT[(cc + 1) * LT + r] = hh.y;
        sHT[(cc + 2) * LT + r] = hh.z; sHT[(cc + 3) * LT + r] = hh.w;
    }
    __syncthreads();

    int c0 = (tid & 15) << 2;
    int n0 = (tid >> 4) << 2;
    float acc[4][4];
#pragma unroll
    for (int i = 0; i < 4; ++i)
#pragma unroll
        for (int j = 0; j < 4; ++j) acc[i][j] = sb[c0 + j];

#pragma unroll 8
    for (int k = 0; k < HID; ++k) {
        float4 wl = *(const float4*)&sWl[k * HID + c0];
        float4 wr = *(const float4*)&sWr[k * HID + c0];
        float4 a4 = *(const float4*)&sAT[k * LT + n0];
        float4 h4 = *(const float4*)&sHT[k * LT + n0];
        const float* ap = (const float*)&a4;
        const float* hp = (const float*)&h4;
        const float* wlp = (const float*)&wl;
        const float* wrp = (const float*)&wr;
#pragma unroll
        for (int i = 0; i < 4; ++i)
#pragma unroll
            for (int j = 0; j < 4; ++j)
                acc[i][j] += ap[i] * wlp[j] + hp[i] * wrp[j];
    }

#pragma unroll
    for (int i = 0; i < 4; ++i) {
        int n = node0 + n0 + i;
        if (n < N_NODES) {
            float4 o4;
            o4.x = fmaxf(acc[i][0], 0.f);
            o4.y = fmaxf(acc[i][1], 0.f);
            o4.z = fmaxf(acc[i][2], 0.f);
            o4.w = fmaxf(acc[i][3], 0.f);
            *(float4*)(out + (size_t)n * HID + c0) = o4;
        }
    }
}

// ---- final head: out = h @ Wlin + blin (fp32 out) -------------------------
__global__ void __launch_bounds__(256) final_kernel(
        const float* __restrict__ h, const float* __restrict__ W,
        const float* __restrict__ b, float* __restrict__ out) {
    __shared__ float sW[HID * OUT_CH];
    __shared__ float sb[OUT_CH];
    int tid = threadIdx.x;
    for (int i = tid; i < HID * OUT_CH; i += 256) sW[i] = W[i];
    if (tid < OUT_CH) sb[tid] = b[tid];
    __syncthreads();

    int node = blockIdx.x * 8 + (tid >> 5);
    if (node >= N_NODES) return;
    int o = tid & 31;
    const float* hr = h + (size_t)node * HID;
    float acc = sb[o];
#pragma unroll 8
    for (int k = 0; k < HID; k++) acc += hr[k] * sW[k * OUT_CH + o];
    out[(size_t)node * OUT_CH + o] = acc;
}

extern "C" void kernel_launch(void* const* d_in, const int* in_sizes, int n_in,
                              void* d_out, int out_size, void* d_ws, size_t ws_size,
                              hipStream_t stream) {
    const float* x    = (const float*)d_in[0];
    const int*   ei   = (const int*)d_in[1];
    const float* Wl1  = (const float*)d_in[2];
    const float* Wr1  = (const float*)d_in[3];
    const float* b1   = (const float*)d_in[4];
    const float* Wl2  = (const float*)d_in[5];
    const float* Wr2  = (const float*)d_in[6];
    const float* b2   = (const float*)d_in[7];
    const float* Wl3  = (const float*)d_in[8];
    const float* Wr3  = (const float*)d_in[9];
    const float* b3   = (const float*)d_in[10];
    const float* Wlin = (const float*)d_in[11];
    const float* blin = (const float*)d_in[12];
    float* out = (float*)d_out;

    // workspace layout (4-byte elements), ~58.4 MB total
    int* ip     = (int*)d_ws;
    int* flag   = ip;                    // 128
    int* off    = flag + 128;            // 100001 (reserve 100224)
    int* cursor = off + 100224;          // 100096 (doubles as counts)
    int* bsum   = cursor + 100096;       // 512
    int* csr    = bsum + 512;            // 1600000
    float* agg  = (float*)(csr + N_EDGES);        // 6.4M floats
    float* feat = agg + (size_t)N_NODES * HID;    // 6.4M floats

    const int EB = (N_EDGES + 255) / 256;        // 6250
    const int GATHER_BLOCKS = (N_NODES + 3) / 4; // 25000
    const int LAYER_BLOCKS = (N_NODES + 63) / 64;// 1563
    const int FINAL_BLOCKS = (N_NODES + 7) / 8;  // 12500

    // CSR build
    detect_kernel<<<1, 64, 0, stream>>>(ei, flag);
    hipMemsetAsync(cursor, 0, (size_t)N_NODES * 4, stream);
    count_kernel<<<EB, 256, 0, stream>>>(ei, flag, cursor);
    blockscan_kernel<<<NBLK_SCAN, 256, 0, stream>>>(cursor, off, bsum);
    topscan_kernel<<<1, 512, 0, stream>>>(bsum);
    addback_kernel<<<NBLK_SCAN, 256, 0, stream>>>(off, bsum, cursor);
    fill_kernel<<<EB, 256, 0, stream>>>(ei, flag, cursor, csr);

    // layer 1: x -> feat
    gather_kernel<<<GATHER_BLOCKS, 256, 0, stream>>>(x, off, csr, agg);
    layer_kernel<<<LAYER_BLOCKS, 256, 0, stream>>>(agg, x, Wl1, Wr1, b1, feat);

    // layer 2: feat -> feat (in-place safe: per-block tile staged before write)
    gather_kernel<<<GATHER_BLOCKS, 256, 0, stream>>>(feat, off, csr, agg);
    layer_kernel<<<LAYER_BLOCKS, 256, 0, stream>>>(agg, feat, Wl2, Wr2, b2, feat);

    // layer 3
    gather_kernel<<<GATHER_BLOCKS, 256, 0, stream>>>(feat, off, csr, agg);
    layer_kernel<<<LAYER_BLOCKS, 256, 0, stream>>>(agg, feat, Wl3, Wr3, b3, feat);

    // head
    final_kernel<<<FINAL_BLOCKS, 256, 0, stream>>>(feat, Wlin, blin, out);
}